// Round 2
// baseline (73.626 us; speedup 1.0000x reference)
//
#include <hip/hip_runtime.h>
#include <math.h>

#define BB 8
#define HH 480
#define WW 640
#define CC 5
#define HW (HH * WW)

// stats layout (doubles in d_ws):
// [0]              : global L1 sum
// [1 .. 8]         : per-b mask sum
// [9 .. 9+200)     : per (b,c): idx = 9 + b*25 + c*5 + k
//                    k: 0=sum(pm) 1=sum(gm) 2=sum(pm*gm) 3=sum(pm*pm) 4=sum(gm*gm)
#define NSTATS 209
#define GRAY2_OFFSET 4096

__device__ __forceinline__ float fast_tanh5(float d) {
    // tanh(5d) = (1 - e^{-10d}) / (1 + e^{-10d})
    float ez = __expf(-10.0f * d);
    return (1.0f - ez) * __builtin_amdgcn_rcpf(1.0f + ez);
}

__global__ __launch_bounds__(256) void k_gray2(const float* __restrict__ img2,
                                               float* __restrict__ gray2,
                                               double* __restrict__ stats) {
    if (blockIdx.x == 0 && threadIdx.x < NSTATS) stats[threadIdx.x] = 0.0;
    int gid = blockIdx.x * blockDim.x + threadIdx.x;
    int idx4 = gid * 4;
    if (idx4 >= BB * HW) return;
    int b = idx4 / HW;
    int p = idx4 - b * HW;
    const float* base = img2 + (size_t)b * 3 * HW + p;
    float4 r = *(const float4*)(base);
    float4 g = *(const float4*)(base + HW);
    float4 bl = *(const float4*)(base + 2 * HW);
    float4 o;
    o.x = 0.299f * r.x + 0.587f * g.x + 0.114f * bl.x;
    o.y = 0.299f * r.y + 0.587f * g.y + 0.114f * bl.y;
    o.z = 0.299f * r.z + 0.587f * g.z + 0.114f * bl.z;
    o.w = 0.299f * r.w + 0.587f * g.w + 0.114f * bl.w;
    *(float4*)(gray2 + idx4) = o;
}

__global__ __launch_bounds__(256) void k_main(
    const float* __restrict__ img1, const float* __restrict__ flow,
    const float* __restrict__ ev, const float* __restrict__ vmask,
    const float* __restrict__ gray2, float* __restrict__ pred_out,
    double* __restrict__ stats)
{
    const int b = blockIdx.y;
    const float* i1  = img1  + (size_t)b * 3 * HW;
    const float* fl  = flow  + (size_t)b * 2 * HW;
    const float* evb = ev    + (size_t)b * CC * HW;
    const float* vm  = vmask + (size_t)b * HW;
    const float* g2  = gray2 + (size_t)b * HW;
    float* po = pred_out + (size_t)b * CC * HW;

    const int t  = blockIdx.x * blockDim.x + threadIdx.x;   // 0..76799
    const int p4 = t * 4;                                   // 4 px, same row
    const int py = p4 / WW;
    const int px0 = p4 - py * WW;

    float4 c0 = *(const float4*)(i1 + p4);
    float4 c1 = *(const float4*)(i1 + HW + p4);
    float4 c2 = *(const float4*)(i1 + 2 * HW + p4);
    float4 fx4 = *(const float4*)(fl + p4);
    float4 fy4 = *(const float4*)(fl + HW + p4);
    float4 vm4 = *(const float4*)(vm + p4);
    float4 ev4[CC];
#pragma unroll
    for (int c = 0; c < CC; ++c) ev4[c] = *(const float4*)(evb + c * HW + p4);

    float g1a[4] = {
        0.299f * c0.x + 0.587f * c1.x + 0.114f * c2.x,
        0.299f * c0.y + 0.587f * c1.y + 0.114f * c2.y,
        0.299f * c0.z + 0.587f * c1.z + 0.114f * c2.z,
        0.299f * c0.w + 0.587f * c1.w + 0.114f * c2.w };
    float fxa[4] = { fx4.x, fx4.y, fx4.z, fx4.w };
    float fya[4] = { fy4.x, fy4.y, fy4.z, fy4.w };
    float vma[4] = { vm4.x, vm4.y, vm4.z, vm4.w };

    // acc[0]=l1, acc[1]=masksum, acc[2 + c*5 + k]
    float acc[27];
#pragma unroll
    for (int i = 0; i < 27; ++i) acc[i] = 0.0f;

#pragma unroll
    for (int j = 0; j < 4; ++j) {
        float fx = fxa[j], fy = fya[j];
        float x = (float)(px0 + j) + fx;
        float y = (float)py + fy;
        float x0f = floorf(x);
        float y0f = floorf(y);
        float wx = x - x0f;
        float wy = y - y0f;
        int x0 = (int)x0f;
        int y0 = (int)y0f;
        int x1 = x0 + 1;
        int y1 = y0 + 1;

        float t00 = 0.0f, t10 = 0.0f, t01 = 0.0f, t11 = 0.0f;
        bool xin0 = (x0 >= 0) & (x0 < WW);
        bool xin1 = (x1 >= 0) & (x1 < WW);
        bool yin0 = (y0 >= 0) & (y0 < HH);
        bool yin1 = (y1 >= 0) & (y1 < HH);
        if (yin0) {
            if (xin0) t00 = g2[y0 * WW + x0];
            if (xin1) t10 = g2[y0 * WW + x1];
        }
        if (yin1) {
            if (xin0) t01 = g2[y1 * WW + x0];
            if (xin1) t11 = g2[y1 * WW + x1];
        }
        float warp = t00 * (1.0f - wx) * (1.0f - wy)
                   + t10 * wx * (1.0f - wy)
                   + t01 * (1.0f - wx) * wy
                   + t11 * wx * wy;

        float nc  = fast_tanh5(warp - g1a[j]);
        float pos = fmaxf(nc, 0.0f);
        float neg = fmaxf(-nc, 0.0f);

        float pr[CC];
        pr[0] = pos;
        pr[1] = neg;
        pr[2] = 0.25f * pos + 0.75f * neg;
        pr[3] = 0.50f * pos + 0.50f * neg;
        pr[4] = 0.75f * pos + 0.25f * neg;

        float m = ((fx * fx + fy * fy) > 0.01f) ? vma[j] : 0.0f;
        acc[1] += m;

        const float ga[CC] = { ev4[0][j], ev4[1][j], ev4[2][j], ev4[3][j], ev4[4][j] };
#pragma unroll
        for (int c = 0; c < CC; ++c) {
            po[c * HW + p4 + j] = pr[c];
            float pm = pr[c] * m;
            float gm = ga[c] * m;
            acc[0] += fabsf(pm - gm);
            acc[2 + c * 5 + 0] += pm;
            acc[2 + c * 5 + 1] += gm;
            acc[2 + c * 5 + 2] += pm * gm;
            acc[2 + c * 5 + 3] += pm * pm;
            acc[2 + c * 5 + 4] += gm * gm;
        }
    }

    // wave (64-lane) butterfly reduce each accumulator
#pragma unroll
    for (int i = 0; i < 27; ++i) {
        float v = acc[i];
        for (int off = 32; off > 0; off >>= 1) v += __shfl_down(v, off, 64);
        acc[i] = v;
    }

    __shared__ float sdata[4][27];
    int lane = threadIdx.x & 63;
    int wid  = threadIdx.x >> 6;
    if (lane == 0) {
#pragma unroll
        for (int i = 0; i < 27; ++i) sdata[wid][i] = acc[i];
    }
    __syncthreads();

    if (threadIdx.x < 27) {
        int i = threadIdx.x;
        float s = sdata[0][i] + sdata[1][i] + sdata[2][i] + sdata[3][i];
        double* dst;
        if (i == 0)      dst = &stats[0];
        else if (i == 1) dst = &stats[1 + b];
        else             dst = &stats[9 + b * 25 + (i - 2)];
        atomicAdd(dst, (double)s);
    }
}

__global__ void k_final(const double* __restrict__ stats, float* __restrict__ out) {
    int t = threadIdx.x;  // 64 threads
    double contrib = 0.0;
    if (t < BB * CC) {
        int b = t / CC;
        int c = t - b * CC;
        const double* s = stats + 9 + b * 25 + c * 5;
        double Sp = s[0], Sg = s[1], Spg = s[2], Spp = s[3], Sgg = s[4];
        const double N = (double)HW;
        double num  = Spg - Sp * Sg / N;
        double varp = Spp - Sp * Sp / N; if (varp < 0.0) varp = 0.0;
        double varg = Sgg - Sg * Sg / N; if (varg < 0.0) varg = 0.0;
        double den  = sqrt(varp) * sqrt(varg) + 1e-6;
        double corr = num / den;
        bool valid = stats[1 + b] > 0.0;
        contrib = valid ? (1.0 - corr) : 0.0;
    }
    for (int off = 32; off > 0; off >>= 1) contrib += __shfl_down(contrib, off, 64);
    if (t == 0) {
        double msum_total = 0.0;
        for (int b = 0; b < BB; ++b) msum_total += stats[1 + b];
        double mask_sum = (double)CC * msum_total + 1e-6;
        double l1_loss = stats[0] / mask_sum;
        double corr_loss = contrib / (double)(BB * CC);
        out[0] = (float)(l1_loss + 0.5 * corr_loss);
    }
}

extern "C" void kernel_launch(void* const* d_in, const int* in_sizes, int n_in,
                              void* d_out, int out_size, void* d_ws, size_t ws_size,
                              hipStream_t stream) {
    const float* img1  = (const float*)d_in[0];
    const float* img2  = (const float*)d_in[1];
    const float* flow  = (const float*)d_in[2];
    const float* ev    = (const float*)d_in[3];
    const float* vmask = (const float*)d_in[4];
    float* out = (float*)d_out;

    double* stats = (double*)d_ws;
    float* gray2  = (float*)((char*)d_ws + GRAY2_OFFSET);

    int ngroups = BB * HW / 4;                       // 614400
    k_gray2<<<(ngroups + 255) / 256, 256, 0, stream>>>(img2, gray2, stats);

    dim3 grid(HW / 4 / 256, BB);                     // (300, 8)
    k_main<<<grid, 256, 0, stream>>>(img1, flow, ev, vmask, gray2, out + 1, stats);

    k_final<<<1, 64, 0, stream>>>(stats, out);
}

// Round 3
// 64.539 us; speedup vs baseline: 1.1408x; 1.1408x over previous
//
#include <hip/hip_runtime.h>
#include <math.h>

#define BB 8
#define HH 480
#define WW 640
#define CC 5
#define HW (HH * WW)

// stats layout (doubles in d_ws):
// [0]              : global L1 sum
// [1 .. 8]         : per-b mask sum
// [9 .. 9+200)     : per (b,c): idx = 9 + b*25 + c*5 + k
//                    k: 0=sum(pm) 1=sum(gm) 2=sum(pm*gm) 3=sum(pm*pm) 4=sum(gm*gm)
#define NSTATS 209
#define GRAY2_OFFSET 4096

// padded LDS index: +1 float per 32 (keeps 8-lane stride patterns 2-way -> free)
#define LPAD(i) ((i) + ((i) >> 5))

__device__ __forceinline__ float fast_tanh5(float d) {
    // tanh(5d) = (1 - e^{-10d}) / (1 + e^{-10d})
    float ez = __expf(-10.0f * d);
    return (1.0f - ez) * __builtin_amdgcn_rcpf(1.0f + ez);
}

__global__ __launch_bounds__(256) void k_gray2(const float* __restrict__ img2,
                                               float* __restrict__ gray2,
                                               double* __restrict__ stats) {
    if (blockIdx.x == 0 && threadIdx.x < NSTATS) stats[threadIdx.x] = 0.0;
    int gid = blockIdx.x * blockDim.x + threadIdx.x;
    int idx4 = gid * 4;
    if (idx4 >= BB * HW) return;
    int b = idx4 / HW;
    int p = idx4 - b * HW;
    const float* base = img2 + (size_t)b * 3 * HW + p;
    float4 r = *(const float4*)(base);
    float4 g = *(const float4*)(base + HW);
    float4 bl = *(const float4*)(base + 2 * HW);
    float4 o;
    o.x = 0.299f * r.x + 0.587f * g.x + 0.114f * bl.x;
    o.y = 0.299f * r.y + 0.587f * g.y + 0.114f * bl.y;
    o.z = 0.299f * r.z + 0.587f * g.z + 0.114f * bl.z;
    o.w = 0.299f * r.w + 0.587f * g.w + 0.114f * bl.w;
    *(float4*)(gray2 + idx4) = o;
}

__global__ __launch_bounds__(256) void k_main(
    const float* __restrict__ img1, const float* __restrict__ flow,
    const float* __restrict__ ev, const float* __restrict__ vmask,
    const float* __restrict__ gray2, float* __restrict__ pred_out,
    double* __restrict__ stats)
{
    const int b = blockIdx.y;
    const float* i1  = img1  + (size_t)b * 3 * HW;
    const float* fl  = flow  + (size_t)b * 2 * HW;
    const float* evb = ev    + (size_t)b * CC * HW;
    const float* vm  = vmask + (size_t)b * HW;
    const float* g2  = gray2 + (size_t)b * HW;
    float* po = pred_out + (size_t)b * CC * HW;   // NOTE: 4B-aligned only (out+1)

    const int tid = threadIdx.x;
    const int P   = blockIdx.x * 1024;            // block owns px [P, P+1024)
    const int p4  = P + 4 * tid;                  // 4 px, same row (p4 % 4 == 0)
    const int py  = p4 / WW;
    const int px0 = p4 - py * WW;

    __shared__ float s_pr[CC][1056];              // 1024 + 32 pad
    __shared__ float sdata[4][27];

    float4 c0 = *(const float4*)(i1 + p4);
    float4 c1 = *(const float4*)(i1 + HW + p4);
    float4 c2 = *(const float4*)(i1 + 2 * HW + p4);
    float4 fx4 = *(const float4*)(fl + p4);
    float4 fy4 = *(const float4*)(fl + HW + p4);
    float4 vm4 = *(const float4*)(vm + p4);
    float4 ev4[CC];
#pragma unroll
    for (int c = 0; c < CC; ++c) ev4[c] = *(const float4*)(evb + c * HW + p4);

    float g1a[4] = {
        0.299f * c0.x + 0.587f * c1.x + 0.114f * c2.x,
        0.299f * c0.y + 0.587f * c1.y + 0.114f * c2.y,
        0.299f * c0.z + 0.587f * c1.z + 0.114f * c2.z,
        0.299f * c0.w + 0.587f * c1.w + 0.114f * c2.w };
    float fxa[4] = { fx4.x, fx4.y, fx4.z, fx4.w };
    float fya[4] = { fy4.x, fy4.y, fy4.z, fy4.w };
    float vma[4] = { vm4.x, vm4.y, vm4.z, vm4.w };

    // acc[0]=l1, acc[1]=masksum, acc[2 + c*5 + k]
    float acc[27];
#pragma unroll
    for (int i = 0; i < 27; ++i) acc[i] = 0.0f;

#pragma unroll
    for (int j = 0; j < 4; ++j) {
        float fx = fxa[j], fy = fya[j];
        float x = (float)(px0 + j) + fx;
        float y = (float)py + fy;
        float x0f = floorf(x);
        float y0f = floorf(y);
        float wx = x - x0f;
        float wy = y - y0f;
        int x0 = (int)x0f;
        int y0 = (int)y0f;
        int x1 = x0 + 1;
        int y1 = y0 + 1;

        float t00 = 0.0f, t10 = 0.0f, t01 = 0.0f, t11 = 0.0f;
        bool xin0 = (x0 >= 0) & (x0 < WW);
        bool xin1 = (x1 >= 0) & (x1 < WW);
        bool yin0 = (y0 >= 0) & (y0 < HH);
        bool yin1 = (y1 >= 0) & (y1 < HH);
        if (yin0) {
            if (xin0) t00 = g2[y0 * WW + x0];
            if (xin1) t10 = g2[y0 * WW + x1];
        }
        if (yin1) {
            if (xin0) t01 = g2[y1 * WW + x0];
            if (xin1) t11 = g2[y1 * WW + x1];
        }
        float warp = t00 * (1.0f - wx) * (1.0f - wy)
                   + t10 * wx * (1.0f - wy)
                   + t01 * (1.0f - wx) * wy
                   + t11 * wx * wy;

        float nc  = fast_tanh5(warp - g1a[j]);
        float pos = fmaxf(nc, 0.0f);
        float neg = fmaxf(-nc, 0.0f);

        float pr[CC];
        pr[0] = pos;
        pr[1] = neg;
        pr[2] = 0.25f * pos + 0.75f * neg;
        pr[3] = 0.50f * pos + 0.50f * neg;
        pr[4] = 0.75f * pos + 0.25f * neg;

        const int li = LPAD(4 * tid + j);
#pragma unroll
        for (int c = 0; c < CC; ++c) s_pr[c][li] = pr[c];

        float m = ((fx * fx + fy * fy) > 0.01f) ? vma[j] : 0.0f;
        acc[1] += m;

        const float ga[CC] = { ev4[0][j], ev4[1][j], ev4[2][j], ev4[3][j], ev4[4][j] };
#pragma unroll
        for (int c = 0; c < CC; ++c) {
            float pm = pr[c] * m;
            float gm = ga[c] * m;
            acc[0] += fabsf(pm - gm);
            acc[2 + c * 5 + 0] += pm;
            acc[2 + c * 5 + 1] += gm;
            acc[2 + c * 5 + 2] += pm * gm;
            acc[2 + c * 5 + 3] += pm * pm;
            acc[2 + c * 5 + 4] += gm * gm;
        }
    }

    __syncthreads();

    // re-staggered pred stores: out index = 1 + ... + px, so px = 4k+3 is 16B-aligned
#pragma unroll
    for (int c = 0; c < CC; ++c) {
        const float* sp = s_pr[c];
        float* ob = po + c * HW + P;
        if (tid < 255) {
            int i0 = 3 + 4 * tid;
            float4 v;
            v.x = sp[LPAD(i0)];
            v.y = sp[LPAD(i0 + 1)];
            v.z = sp[LPAD(i0 + 2)];
            v.w = sp[LPAD(i0 + 3)];
            *(float4*)(ob + i0) = v;
        } else {
            ob[0] = sp[LPAD(0)];
            ob[1] = sp[LPAD(1)];
            ob[2] = sp[LPAD(2)];
            ob[1023] = sp[LPAD(1023)];
        }
    }

    // wave (64-lane) butterfly reduce each accumulator
#pragma unroll
    for (int i = 0; i < 27; ++i) {
        float v = acc[i];
        for (int off = 32; off > 0; off >>= 1) v += __shfl_down(v, off, 64);
        acc[i] = v;
    }

    int lane = tid & 63;
    int wid  = tid >> 6;
    if (lane == 0) {
#pragma unroll
        for (int i = 0; i < 27; ++i) sdata[wid][i] = acc[i];
    }
    __syncthreads();

    if (tid < 27) {
        int i = tid;
        float s = sdata[0][i] + sdata[1][i] + sdata[2][i] + sdata[3][i];
        double* dst;
        if (i == 0)      dst = &stats[0];
        else if (i == 1) dst = &stats[1 + b];
        else             dst = &stats[9 + b * 25 + (i - 2)];
        atomicAdd(dst, (double)s);
    }
}

__global__ void k_final(const double* __restrict__ stats, float* __restrict__ out) {
    int t = threadIdx.x;  // 64 threads
    double contrib = 0.0;
    if (t < BB * CC) {
        int b = t / CC;
        int c = t - b * CC;
        const double* s = stats + 9 + b * 25 + c * 5;
        double Sp = s[0], Sg = s[1], Spg = s[2], Spp = s[3], Sgg = s[4];
        const double N = (double)HW;
        double num  = Spg - Sp * Sg / N;
        double varp = Spp - Sp * Sp / N; if (varp < 0.0) varp = 0.0;
        double varg = Sgg - Sg * Sg / N; if (varg < 0.0) varg = 0.0;
        double den  = sqrt(varp) * sqrt(varg) + 1e-6;
        double corr = num / den;
        bool valid = stats[1 + b] > 0.0;
        contrib = valid ? (1.0 - corr) : 0.0;
    }
    for (int off = 32; off > 0; off >>= 1) contrib += __shfl_down(contrib, off, 64);
    if (t == 0) {
        double msum_total = 0.0;
        for (int b = 0; b < BB; ++b) msum_total += stats[1 + b];
        double mask_sum = (double)CC * msum_total + 1e-6;
        double l1_loss = stats[0] / mask_sum;
        double corr_loss = contrib / (double)(BB * CC);
        out[0] = (float)(l1_loss + 0.5 * corr_loss);
    }
}

extern "C" void kernel_launch(void* const* d_in, const int* in_sizes, int n_in,
                              void* d_out, int out_size, void* d_ws, size_t ws_size,
                              hipStream_t stream) {
    const float* img1  = (const float*)d_in[0];
    const float* img2  = (const float*)d_in[1];
    const float* flow  = (const float*)d_in[2];
    const float* ev    = (const float*)d_in[3];
    const float* vmask = (const float*)d_in[4];
    float* out = (float*)d_out;

    double* stats = (double*)d_ws;
    float* gray2  = (float*)((char*)d_ws + GRAY2_OFFSET);

    int ngroups = BB * HW / 4;                       // 614400
    k_gray2<<<(ngroups + 255) / 256, 256, 0, stream>>>(img2, gray2, stats);

    dim3 grid(HW / 1024, BB);                        // (300, 8)
    k_main<<<grid, 256, 0, stream>>>(img1, flow, ev, vmask, gray2, out + 1, stats);

    k_final<<<1, 64, 0, stream>>>(stats, out);
}

// Round 4
// 62.832 us; speedup vs baseline: 1.1718x; 1.0272x over previous
//
#include <hip/hip_runtime.h>
#include <math.h>

#define BB 8
#define HH 480
#define WW 640
#define CC 5
#define HW (HH * WW)

// stats layout (doubles in d_ws):
// [0]              : global L1 sum
// [1 .. 8]         : per-b mask sum
// [9 .. 9+200)     : per (b,c): idx = 9 + b*25 + c*5 + k
//                    k: 0=sum(pm) 1=sum(gm) 2=sum(pm*gm) 3=sum(pm*pm) 4=sum(gm*gm)
#define NSTATS 209
#define GRAY2_OFFSET 4096

// padded LDS index: +1 float per 32 (keeps strided patterns <=2-way -> free)
#define LPAD(i) ((i) + ((i) >> 5))

__device__ __forceinline__ float fast_tanh5(float d) {
    // tanh(5d) = (1 - e^{-10d}) / (1 + e^{-10d})
    float ez = __expf(-10.0f * d);
    return (1.0f - ez) * __builtin_amdgcn_rcpf(1.0f + ez);
}

__global__ __launch_bounds__(256) void k_gray2(const float* __restrict__ img2,
                                               float* __restrict__ gray2,
                                               double* __restrict__ stats) {
    if (blockIdx.x == 0 && threadIdx.x < NSTATS) stats[threadIdx.x] = 0.0;
    int gid = blockIdx.x * blockDim.x + threadIdx.x;
    int idx4 = gid * 4;
    if (idx4 >= BB * HW) return;
    int b = idx4 / HW;
    int p = idx4 - b * HW;
    const float* base = img2 + (size_t)b * 3 * HW + p;
    float4 r = *(const float4*)(base);
    float4 g = *(const float4*)(base + HW);
    float4 bl = *(const float4*)(base + 2 * HW);
    float4 o;
    o.x = 0.299f * r.x + 0.587f * g.x + 0.114f * bl.x;
    o.y = 0.299f * r.y + 0.587f * g.y + 0.114f * bl.y;
    o.z = 0.299f * r.z + 0.587f * g.z + 0.114f * bl.z;
    o.w = 0.299f * r.w + 0.587f * g.w + 0.114f * bl.w;
    *(float4*)(gray2 + idx4) = o;
}

__global__ __launch_bounds__(256) void k_main(
    const float* __restrict__ img1, const float* __restrict__ flow,
    const float* __restrict__ ev, const float* __restrict__ vmask,
    const float* __restrict__ gray2, float* __restrict__ pred_out,
    double* __restrict__ stats)
{
    const int b = blockIdx.y;
    const float* i1  = img1  + (size_t)b * 3 * HW;
    const float* fl  = flow  + (size_t)b * 2 * HW;
    const float* evb = ev    + (size_t)b * CC * HW;
    const float* vm  = vmask + (size_t)b * HW;
    const float* g2  = gray2 + (size_t)b * HW;
    float* po = pred_out + (size_t)b * CC * HW;   // NOTE: 4B-aligned only (out+1)

    const int tid = threadIdx.x;
    const int P   = blockIdx.x * 1024;            // block owns px [P, P+1024)
    const int p4  = P + 4 * tid;                  // 4 px, same row
    const int py  = p4 / WW;
    const int px0 = p4 - py * WW;

    __shared__ float s_pr[CC][1056];              // 1024 + 32 pad
    __shared__ float sdata[4][27];

    float4 c0 = *(const float4*)(i1 + p4);
    float4 c1 = *(const float4*)(i1 + HW + p4);
    float4 c2 = *(const float4*)(i1 + 2 * HW + p4);
    float4 fx4 = *(const float4*)(fl + p4);
    float4 fy4 = *(const float4*)(fl + HW + p4);
    float4 vm4 = *(const float4*)(vm + p4);
    float4 ev4[CC];
#pragma unroll
    for (int c = 0; c < CC; ++c) ev4[c] = *(const float4*)(evb + c * HW + p4);

    float fxa[4] = { fx4.x, fx4.y, fx4.z, fx4.w };
    float fya[4] = { fy4.x, fy4.y, fy4.z, fy4.w };
    float vma[4] = { vm4.x, vm4.y, vm4.z, vm4.w };

    // ---- branchless gather: compute all 16 addresses+weights, then 16 loads ----
    int   adr[4][4];
    float wgt[4][4];
#pragma unroll
    for (int j = 0; j < 4; ++j) {
        float fx = fxa[j], fy = fya[j];
        float x = (float)(px0 + j) + fx;
        float y = (float)py + fy;
        float x0f = floorf(x);
        float y0f = floorf(y);
        float wx = x - x0f;
        float wy = y - y0f;
        int x0 = (int)x0f, y0 = (int)y0f;
        int x1 = x0 + 1,   y1 = y0 + 1;
        int cx0 = min(max(x0, 0), WW - 1);
        int cx1 = min(max(x1, 0), WW - 1);
        int cy0 = min(max(y0, 0), HH - 1);
        int cy1 = min(max(y1, 0), HH - 1);
        float ix0 = (x0 >= 0 && x0 < WW) ? 1.0f : 0.0f;
        float ix1 = (x1 >= 0 && x1 < WW) ? 1.0f : 0.0f;
        float iy0 = (y0 >= 0 && y0 < HH) ? 1.0f : 0.0f;
        float iy1 = (y1 >= 0 && y1 < HH) ? 1.0f : 0.0f;
        adr[j][0] = cy0 * WW + cx0;
        adr[j][1] = cy0 * WW + cx1;
        adr[j][2] = cy1 * WW + cx0;
        adr[j][3] = cy1 * WW + cx1;
        wgt[j][0] = (1.0f - wx) * (1.0f - wy) * ix0 * iy0;
        wgt[j][1] = wx * (1.0f - wy) * ix1 * iy0;
        wgt[j][2] = (1.0f - wx) * wy * ix0 * iy1;
        wgt[j][3] = wx * wy * ix1 * iy1;
    }
    float tv[4][4];
#pragma unroll
    for (int j = 0; j < 4; ++j)
#pragma unroll
        for (int t = 0; t < 4; ++t) tv[j][t] = g2[adr[j][t]];

    float g1a[4] = {
        0.299f * c0.x + 0.587f * c1.x + 0.114f * c2.x,
        0.299f * c0.y + 0.587f * c1.y + 0.114f * c2.y,
        0.299f * c0.z + 0.587f * c1.z + 0.114f * c2.z,
        0.299f * c0.w + 0.587f * c1.w + 0.114f * c2.w };

    // acc[0]=l1, acc[1]=masksum, acc[2 + c*5 + k]
    float acc[27];
#pragma unroll
    for (int i = 0; i < 27; ++i) acc[i] = 0.0f;

#pragma unroll
    for (int j = 0; j < 4; ++j) {
        float warp = tv[j][0] * wgt[j][0] + tv[j][1] * wgt[j][1]
                   + tv[j][2] * wgt[j][2] + tv[j][3] * wgt[j][3];

        float nc  = fast_tanh5(warp - g1a[j]);
        float pos = fmaxf(nc, 0.0f);
        float neg = fmaxf(-nc, 0.0f);

        float pr[CC];
        pr[0] = pos;
        pr[1] = neg;
        pr[2] = 0.25f * pos + 0.75f * neg;
        pr[3] = 0.50f * pos + 0.50f * neg;
        pr[4] = 0.75f * pos + 0.25f * neg;

        const int li = LPAD(4 * tid + j);
#pragma unroll
        for (int c = 0; c < CC; ++c) s_pr[c][li] = pr[c];

        float fx = fxa[j], fy = fya[j];
        float m = ((fx * fx + fy * fy) > 0.01f) ? vma[j] : 0.0f;
        acc[1] += m;

        const float ga[CC] = { ev4[0][j], ev4[1][j], ev4[2][j], ev4[3][j], ev4[4][j] };
#pragma unroll
        for (int c = 0; c < CC; ++c) {
            float pm = pr[c] * m;
            float gm = ga[c] * m;
            acc[0] += fabsf(pm - gm);
            acc[2 + c * 5 + 0] += pm;
            acc[2 + c * 5 + 1] += gm;
            acc[2 + c * 5 + 2] += pm * gm;
            acc[2 + c * 5 + 3] += pm * pm;
            acc[2 + c * 5 + 4] += gm * gm;
        }
    }

    __syncthreads();

    // re-staggered pred stores: out index = 1 + ... + px, so px = 4k+3 is 16B-aligned
#pragma unroll
    for (int c = 0; c < CC; ++c) {
        const float* sp = s_pr[c];
        float* ob = po + c * HW + P;
        if (tid < 255) {
            int i0 = 3 + 4 * tid;
            float4 v;
            v.x = sp[LPAD(i0)];
            v.y = sp[LPAD(i0 + 1)];
            v.z = sp[LPAD(i0 + 2)];
            v.w = sp[LPAD(i0 + 3)];
            *(float4*)(ob + i0) = v;
        } else {
            ob[0] = sp[LPAD(0)];
            ob[1] = sp[LPAD(1)];
            ob[2] = sp[LPAD(2)];
            ob[1023] = sp[LPAD(1023)];
        }
    }

    // wave (64-lane) butterfly reduce each accumulator
#pragma unroll
    for (int i = 0; i < 27; ++i) {
        float v = acc[i];
        for (int off = 32; off > 0; off >>= 1) v += __shfl_down(v, off, 64);
        acc[i] = v;
    }

    int lane = tid & 63;
    int wid  = tid >> 6;
    if (lane == 0) {
#pragma unroll
        for (int i = 0; i < 27; ++i) sdata[wid][i] = acc[i];
    }
    __syncthreads();

    if (tid < 27) {
        int i = tid;
        float s = sdata[0][i] + sdata[1][i] + sdata[2][i] + sdata[3][i];
        double* dst;
        if (i == 0)      dst = &stats[0];
        else if (i == 1) dst = &stats[1 + b];
        else             dst = &stats[9 + b * 25 + (i - 2)];
        atomicAdd(dst, (double)s);
    }
}

__global__ void k_final(const double* __restrict__ stats, float* __restrict__ out) {
    int t = threadIdx.x;  // 64 threads
    double contrib = 0.0;
    if (t < BB * CC) {
        int b = t / CC;
        int c = t - b * CC;
        const double* s = stats + 9 + b * 25 + c * 5;
        double Sp = s[0], Sg = s[1], Spg = s[2], Spp = s[3], Sgg = s[4];
        const double N = (double)HW;
        double num  = Spg - Sp * Sg / N;
        double varp = Spp - Sp * Sp / N; if (varp < 0.0) varp = 0.0;
        double varg = Sgg - Sg * Sg / N; if (varg < 0.0) varg = 0.0;
        double den  = sqrt(varp) * sqrt(varg) + 1e-6;
        double corr = num / den;
        bool valid = stats[1 + b] > 0.0;
        contrib = valid ? (1.0 - corr) : 0.0;
    }
    for (int off = 32; off > 0; off >>= 1) contrib += __shfl_down(contrib, off, 64);
    if (t == 0) {
        double msum_total = 0.0;
        for (int b = 0; b < BB; ++b) msum_total += stats[1 + b];
        double mask_sum = (double)CC * msum_total + 1e-6;
        double l1_loss = stats[0] / mask_sum;
        double corr_loss = contrib / (double)(BB * CC);
        out[0] = (float)(l1_loss + 0.5 * corr_loss);
    }
}

extern "C" void kernel_launch(void* const* d_in, const int* in_sizes, int n_in,
                              void* d_out, int out_size, void* d_ws, size_t ws_size,
                              hipStream_t stream) {
    const float* img1  = (const float*)d_in[0];
    const float* img2  = (const float*)d_in[1];
    const float* flow  = (const float*)d_in[2];
    const float* ev    = (const float*)d_in[3];
    const float* vmask = (const float*)d_in[4];
    float* out = (float*)d_out;

    double* stats = (double*)d_ws;
    float* gray2  = (float*)((char*)d_ws + GRAY2_OFFSET);

    int ngroups = BB * HW / 4;                       // 614400
    k_gray2<<<(ngroups + 255) / 256, 256, 0, stream>>>(img2, gray2, stats);

    dim3 grid(HW / 1024, BB);                        // (300, 8)
    k_main<<<grid, 256, 0, stream>>>(img1, flow, ev, vmask, gray2, out + 1, stats);

    k_final<<<1, 64, 0, stream>>>(stats, out);
}

// Round 5
// 59.338 us; speedup vs baseline: 1.2408x; 1.0589x over previous
//
#include <hip/hip_runtime.h>
#include <math.h>

#define BB 8
#define HH 480
#define WW 640
#define CC 5
#define HW (HH * WW)

// stats layout (doubles in d_ws):
// [0]              : global L1 sum
// [1 .. 8]         : per-b mask sum
// [9 .. 9+200)     : per (b,c): idx = 9 + b*25 + c*5 + k
//                    k: 0=sum(pm) 1=sum(gm) 2=sum(pm*gm) 3=sum(pm*pm) 4=sum(gm*gm)
#define NSTATS 209
#define GRAY2_OFFSET 4096

// padded LDS index: +1 float per 32 (keeps strided patterns <=2-way -> free)
#define LPAD(i) ((i) + ((i) >> 5))

__device__ __forceinline__ float fast_tanh5(float d) {
    // tanh(5d) = (1 - e^{-10d}) / (1 + e^{-10d})
    float ez = __expf(-10.0f * d);
    return (1.0f - ez) * __builtin_amdgcn_rcpf(1.0f + ez);
}

// Full-wave (64-lane) sum via DPP: row_shr 1,2,4,8 + row_bcast15/31.
// Pure VALU (no LDS pipe). Total lands in lane 63.
__device__ __forceinline__ float wave_sum_dpp(float v) {
    v += __int_as_float(__builtin_amdgcn_update_dpp(0, __float_as_int(v), 0x111, 0xf, 0xf, false));
    v += __int_as_float(__builtin_amdgcn_update_dpp(0, __float_as_int(v), 0x112, 0xf, 0xf, false));
    v += __int_as_float(__builtin_amdgcn_update_dpp(0, __float_as_int(v), 0x114, 0xf, 0xf, false));
    v += __int_as_float(__builtin_amdgcn_update_dpp(0, __float_as_int(v), 0x118, 0xf, 0xf, false));
    v += __int_as_float(__builtin_amdgcn_update_dpp(0, __float_as_int(v), 0x142, 0xa, 0xf, false));
    v += __int_as_float(__builtin_amdgcn_update_dpp(0, __float_as_int(v), 0x143, 0xc, 0xf, false));
    return v;
}

__global__ __launch_bounds__(256) void k_gray2(const float* __restrict__ img2,
                                               float* __restrict__ gray2,
                                               double* __restrict__ stats) {
    if (blockIdx.x == 0 && threadIdx.x < NSTATS) stats[threadIdx.x] = 0.0;
    int gid = blockIdx.x * blockDim.x + threadIdx.x;
    int idx4 = gid * 4;
    if (idx4 >= BB * HW) return;
    int b = idx4 / HW;
    int p = idx4 - b * HW;
    const float* base = img2 + (size_t)b * 3 * HW + p;
    float4 r = *(const float4*)(base);
    float4 g = *(const float4*)(base + HW);
    float4 bl = *(const float4*)(base + 2 * HW);
    float4 o;
    o.x = 0.299f * r.x + 0.587f * g.x + 0.114f * bl.x;
    o.y = 0.299f * r.y + 0.587f * g.y + 0.114f * bl.y;
    o.z = 0.299f * r.z + 0.587f * g.z + 0.114f * bl.z;
    o.w = 0.299f * r.w + 0.587f * g.w + 0.114f * bl.w;
    *(float4*)(gray2 + idx4) = o;
}

__global__ __launch_bounds__(256, 2) void k_main(
    const float* __restrict__ img1, const float* __restrict__ flow,
    const float* __restrict__ ev, const float* __restrict__ vmask,
    const float* __restrict__ gray2, float* __restrict__ pred_out,
    double* __restrict__ stats)
{
    const int b = blockIdx.y;
    const float* i1  = img1  + (size_t)b * 3 * HW;
    const float* fl  = flow  + (size_t)b * 2 * HW;
    const float* evb = ev    + (size_t)b * CC * HW;
    const float* vm  = vmask + (size_t)b * HW;
    const float* g2  = gray2 + (size_t)b * HW;
    float* po = pred_out + (size_t)b * CC * HW;   // NOTE: 4B-aligned only (out+1)

    const int tid = threadIdx.x;
    const int P   = blockIdx.x * 1024;            // block owns px [P, P+1024)
    const int p4  = P + 4 * tid;                  // 4 px, same row
    const int py  = p4 / WW;
    const int px0 = p4 - py * WW;

    __shared__ float s_pr[CC][1056];              // 1024 + 32 pad
    __shared__ float sdata[4][27];

    // ---- phase 1: flow loads (gather addresses depend only on these) ----
    float4 fx4 = *(const float4*)(fl + p4);
    float4 fy4 = *(const float4*)(fl + HW + p4);

    float fxa[4] = { fx4.x, fx4.y, fx4.z, fx4.w };
    float fya[4] = { fy4.x, fy4.y, fy4.z, fy4.w };

    int   adr[4][4];
    float wgt[4][4];
#pragma unroll
    for (int j = 0; j < 4; ++j) {
        float fx = fxa[j], fy = fya[j];
        float x = (float)(px0 + j) + fx;
        float y = (float)py + fy;
        float x0f = floorf(x);
        float y0f = floorf(y);
        float wx = x - x0f;
        float wy = y - y0f;
        int x0 = (int)x0f, y0 = (int)y0f;
        int x1 = x0 + 1,   y1 = y0 + 1;
        int cx0 = min(max(x0, 0), WW - 1);
        int cx1 = min(max(x1, 0), WW - 1);
        int cy0 = min(max(y0, 0), HH - 1);
        int cy1 = min(max(y1, 0), HH - 1);
        float ix0 = (x0 >= 0 && x0 < WW) ? 1.0f : 0.0f;
        float ix1 = (x1 >= 0 && x1 < WW) ? 1.0f : 0.0f;
        float iy0 = (y0 >= 0 && y0 < HH) ? 1.0f : 0.0f;
        float iy1 = (y1 >= 0 && y1 < HH) ? 1.0f : 0.0f;
        adr[j][0] = cy0 * WW + cx0;
        adr[j][1] = cy0 * WW + cx1;
        adr[j][2] = cy1 * WW + cx0;
        adr[j][3] = cy1 * WW + cx1;
        wgt[j][0] = (1.0f - wx) * (1.0f - wy) * ix0 * iy0;
        wgt[j][1] = wx * (1.0f - wy) * ix1 * iy0;
        wgt[j][2] = (1.0f - wx) * wy * ix0 * iy1;
        wgt[j][3] = wx * wy * ix1 * iy1;
    }

    // ---- phase 2: issue all 16 gathers back-to-back ----
    float tv[4][4];
#pragma unroll
    for (int j = 0; j < 4; ++j)
#pragma unroll
        for (int t = 0; t < 4; ++t) tv[j][t] = g2[adr[j][t]];

    // ---- phase 3: independent loads land under the gather latency ----
    float4 c0 = *(const float4*)(i1 + p4);
    float4 c1 = *(const float4*)(i1 + HW + p4);
    float4 c2 = *(const float4*)(i1 + 2 * HW + p4);
    float4 vm4 = *(const float4*)(vm + p4);
    float4 ev4[CC];
#pragma unroll
    for (int c = 0; c < CC; ++c) ev4[c] = *(const float4*)(evb + c * HW + p4);

    float g1a[4] = {
        0.299f * c0.x + 0.587f * c1.x + 0.114f * c2.x,
        0.299f * c0.y + 0.587f * c1.y + 0.114f * c2.y,
        0.299f * c0.z + 0.587f * c1.z + 0.114f * c2.z,
        0.299f * c0.w + 0.587f * c1.w + 0.114f * c2.w };
    float vma[4] = { vm4.x, vm4.y, vm4.z, vm4.w };

    // acc[0]=l1, acc[1]=masksum, acc[2 + c*5 + k]
    float acc[27];
#pragma unroll
    for (int i = 0; i < 27; ++i) acc[i] = 0.0f;

#pragma unroll
    for (int j = 0; j < 4; ++j) {
        float warp = tv[j][0] * wgt[j][0] + tv[j][1] * wgt[j][1]
                   + tv[j][2] * wgt[j][2] + tv[j][3] * wgt[j][3];

        float nc  = fast_tanh5(warp - g1a[j]);
        float pos = fmaxf(nc, 0.0f);
        float neg = fmaxf(-nc, 0.0f);

        float pr[CC];
        pr[0] = pos;
        pr[1] = neg;
        pr[2] = 0.25f * pos + 0.75f * neg;
        pr[3] = 0.50f * pos + 0.50f * neg;
        pr[4] = 0.75f * pos + 0.25f * neg;

        const int li = LPAD(4 * tid + j);
#pragma unroll
        for (int c = 0; c < CC; ++c) s_pr[c][li] = pr[c];

        float fx = fxa[j], fy = fya[j];
        float m = ((fx * fx + fy * fy) > 0.01f) ? vma[j] : 0.0f;
        acc[1] += m;

        const float ga[CC] = { ev4[0][j], ev4[1][j], ev4[2][j], ev4[3][j], ev4[4][j] };
#pragma unroll
        for (int c = 0; c < CC; ++c) {
            float pm = pr[c] * m;
            float gm = ga[c] * m;
            acc[0] += fabsf(pm - gm);
            acc[2 + c * 5 + 0] += pm;
            acc[2 + c * 5 + 1] += gm;
            acc[2 + c * 5 + 2] += pm * gm;
            acc[2 + c * 5 + 3] += pm * pm;
            acc[2 + c * 5 + 4] += gm * gm;
        }
    }

    // ---- wave reduce on the VALU (DPP), result in lane 63 ----
    const int lane = tid & 63;
    const int wid  = tid >> 6;
#pragma unroll
    for (int i = 0; i < 27; ++i) acc[i] = wave_sum_dpp(acc[i]);
    if (lane == 63) {
#pragma unroll
        for (int i = 0; i < 27; ++i) sdata[wid][i] = acc[i];
    }

    __syncthreads();   // single barrier: covers s_pr and sdata

    // re-staggered pred stores: out index = 1 + ... + px, so px = 4k+3 is 16B-aligned
#pragma unroll
    for (int c = 0; c < CC; ++c) {
        const float* sp = s_pr[c];
        float* ob = po + c * HW + P;
        if (tid < 255) {
            int i0 = 3 + 4 * tid;
            float4 v;
            v.x = sp[LPAD(i0)];
            v.y = sp[LPAD(i0 + 1)];
            v.z = sp[LPAD(i0 + 2)];
            v.w = sp[LPAD(i0 + 3)];
            *(float4*)(ob + i0) = v;
        } else {
            ob[0] = sp[LPAD(0)];
            ob[1] = sp[LPAD(1)];
            ob[2] = sp[LPAD(2)];
            ob[1023] = sp[LPAD(1023)];
        }
    }

    if (tid < 27) {
        int i = tid;
        float s = sdata[0][i] + sdata[1][i] + sdata[2][i] + sdata[3][i];
        double* dst;
        if (i == 0)      dst = &stats[0];
        else if (i == 1) dst = &stats[1 + b];
        else             dst = &stats[9 + b * 25 + (i - 2)];
        atomicAdd(dst, (double)s);
    }
}

__global__ void k_final(const double* __restrict__ stats, float* __restrict__ out) {
    int t = threadIdx.x;  // 64 threads
    double contrib = 0.0;
    if (t < BB * CC) {
        int b = t / CC;
        int c = t - b * CC;
        const double* s = stats + 9 + b * 25 + c * 5;
        double Sp = s[0], Sg = s[1], Spg = s[2], Spp = s[3], Sgg = s[4];
        const double N = (double)HW;
        double num  = Spg - Sp * Sg / N;
        double varp = Spp - Sp * Sp / N; if (varp < 0.0) varp = 0.0;
        double varg = Sgg - Sg * Sg / N; if (varg < 0.0) varg = 0.0;
        double den  = sqrt(varp) * sqrt(varg) + 1e-6;
        double corr = num / den;
        bool valid = stats[1 + b] > 0.0;
        contrib = valid ? (1.0 - corr) : 0.0;
    }
    for (int off = 32; off > 0; off >>= 1) contrib += __shfl_down(contrib, off, 64);
    if (t == 0) {
        double msum_total = 0.0;
        for (int b = 0; b < BB; ++b) msum_total += stats[1 + b];
        double mask_sum = (double)CC * msum_total + 1e-6;
        double l1_loss = stats[0] / mask_sum;
        double corr_loss = contrib / (double)(BB * CC);
        out[0] = (float)(l1_loss + 0.5 * corr_loss);
    }
}

extern "C" void kernel_launch(void* const* d_in, const int* in_sizes, int n_in,
                              void* d_out, int out_size, void* d_ws, size_t ws_size,
                              hipStream_t stream) {
    const float* img1  = (const float*)d_in[0];
    const float* img2  = (const float*)d_in[1];
    const float* flow  = (const float*)d_in[2];
    const float* ev    = (const float*)d_in[3];
    const float* vmask = (const float*)d_in[4];
    float* out = (float*)d_out;

    double* stats = (double*)d_ws;
    float* gray2  = (float*)((char*)d_ws + GRAY2_OFFSET);

    int ngroups = BB * HW / 4;                       // 614400
    k_gray2<<<(ngroups + 255) / 256, 256, 0, stream>>>(img2, gray2, stats);

    dim3 grid(HW / 1024, BB);                        // (300, 8)
    k_main<<<grid, 256, 0, stream>>>(img1, flow, ev, vmask, gray2, out + 1, stats);

    k_final<<<1, 64, 0, stream>>>(stats, out);
}

// Round 6
// 49.209 us; speedup vs baseline: 1.4962x; 1.2058x over previous
//
#include <hip/hip_runtime.h>
#include <math.h>

#define BB 8
#define HH 480
#define WW 640
#define CC 5
#define HW (HH * WW)
#define NBLK 300   // k_main blocks per image

// d_ws layout:
// [0 .. 4096)                 : stats doubles
//     stats[1..8]   per-b mask sum
//     stats[9+b*25+c*5+k]     per (b,c) moments k: 0=S(pm) 1=S(gm) 2=S(pm*gm) 3=S(pm^2) 4=S(gm^2)
//     stats[210+b]  per-b L1 sum
// [PARTIAL_OFFSET, +2400*32*4): per-block float partials [b*NBLK+bx][32]
// [GRAY2_OFFSET, +9.83MB)     : gray2 planes
#define PARTIAL_OFFSET 4096
#define GRAY2_OFFSET (PARTIAL_OFFSET + 2400 * 32 * 4)

// padded LDS index: +1 float per 32 (keeps strided patterns <=2-way -> free)
#define LPAD(i) ((i) + ((i) >> 5))

__device__ __forceinline__ float fast_tanh5(float d) {
    // tanh(5d) = (1 - e^{-10d}) / (1 + e^{-10d})
    float ez = __expf(-10.0f * d);
    return (1.0f - ez) * __builtin_amdgcn_rcpf(1.0f + ez);
}

// Full-wave (64-lane) sum via DPP: row_shr 1,2,4,8 + row_bcast15/31.
// Pure VALU (no LDS pipe). Total lands in lane 63.
__device__ __forceinline__ float wave_sum_dpp(float v) {
    v += __int_as_float(__builtin_amdgcn_update_dpp(0, __float_as_int(v), 0x111, 0xf, 0xf, false));
    v += __int_as_float(__builtin_amdgcn_update_dpp(0, __float_as_int(v), 0x112, 0xf, 0xf, false));
    v += __int_as_float(__builtin_amdgcn_update_dpp(0, __float_as_int(v), 0x114, 0xf, 0xf, false));
    v += __int_as_float(__builtin_amdgcn_update_dpp(0, __float_as_int(v), 0x118, 0xf, 0xf, false));
    v += __int_as_float(__builtin_amdgcn_update_dpp(0, __float_as_int(v), 0x142, 0xa, 0xf, false));
    v += __int_as_float(__builtin_amdgcn_update_dpp(0, __float_as_int(v), 0x143, 0xc, 0xf, false));
    return v;
}

__global__ __launch_bounds__(256) void k_gray2(const float* __restrict__ img2,
                                               float* __restrict__ gray2) {
    int gid = blockIdx.x * blockDim.x + threadIdx.x;
    int idx4 = gid * 4;
    if (idx4 >= BB * HW) return;
    int b = idx4 / HW;
    int p = idx4 - b * HW;
    const float* base = img2 + (size_t)b * 3 * HW + p;
    float4 r = *(const float4*)(base);
    float4 g = *(const float4*)(base + HW);
    float4 bl = *(const float4*)(base + 2 * HW);
    float4 o;
    o.x = 0.299f * r.x + 0.587f * g.x + 0.114f * bl.x;
    o.y = 0.299f * r.y + 0.587f * g.y + 0.114f * bl.y;
    o.z = 0.299f * r.z + 0.587f * g.z + 0.114f * bl.z;
    o.w = 0.299f * r.w + 0.587f * g.w + 0.114f * bl.w;
    *(float4*)(gray2 + idx4) = o;
}

__global__ __launch_bounds__(256, 2) void k_main(
    const float* __restrict__ img1, const float* __restrict__ flow,
    const float* __restrict__ ev, const float* __restrict__ vmask,
    const float* __restrict__ gray2, float* __restrict__ pred_out,
    float* __restrict__ partial)
{
    const int b = blockIdx.y;
    const float* i1  = img1  + (size_t)b * 3 * HW;
    const float* fl  = flow  + (size_t)b * 2 * HW;
    const float* evb = ev    + (size_t)b * CC * HW;
    const float* vm  = vmask + (size_t)b * HW;
    const float* g2  = gray2 + (size_t)b * HW;
    float* po = pred_out + (size_t)b * CC * HW;   // NOTE: 4B-aligned only (out+1)

    const int tid = threadIdx.x;
    const int P   = blockIdx.x * 1024;            // block owns px [P, P+1024)
    const int p4  = P + 4 * tid;                  // 4 px, same row
    const int py  = p4 / WW;
    const int px0 = p4 - py * WW;

    __shared__ float s_pr[CC][1056];              // 1024 + 32 pad
    __shared__ float sdata[4][27];

    // ---- phase 1: flow loads (gather addresses depend only on these) ----
    float4 fx4 = *(const float4*)(fl + p4);
    float4 fy4 = *(const float4*)(fl + HW + p4);

    float fxa[4] = { fx4.x, fx4.y, fx4.z, fx4.w };
    float fya[4] = { fy4.x, fy4.y, fy4.z, fy4.w };

    int   adr[4][4];
    float wgt[4][4];
#pragma unroll
    for (int j = 0; j < 4; ++j) {
        float fx = fxa[j], fy = fya[j];
        float x = (float)(px0 + j) + fx;
        float y = (float)py + fy;
        float x0f = floorf(x);
        float y0f = floorf(y);
        float wx = x - x0f;
        float wy = y - y0f;
        int x0 = (int)x0f, y0 = (int)y0f;
        int x1 = x0 + 1,   y1 = y0 + 1;
        int cx0 = min(max(x0, 0), WW - 1);
        int cx1 = min(max(x1, 0), WW - 1);
        int cy0 = min(max(y0, 0), HH - 1);
        int cy1 = min(max(y1, 0), HH - 1);
        float ix0 = (x0 >= 0 && x0 < WW) ? 1.0f : 0.0f;
        float ix1 = (x1 >= 0 && x1 < WW) ? 1.0f : 0.0f;
        float iy0 = (y0 >= 0 && y0 < HH) ? 1.0f : 0.0f;
        float iy1 = (y1 >= 0 && y1 < HH) ? 1.0f : 0.0f;
        adr[j][0] = cy0 * WW + cx0;
        adr[j][1] = cy0 * WW + cx1;
        adr[j][2] = cy1 * WW + cx0;
        adr[j][3] = cy1 * WW + cx1;
        wgt[j][0] = (1.0f - wx) * (1.0f - wy) * ix0 * iy0;
        wgt[j][1] = wx * (1.0f - wy) * ix1 * iy0;
        wgt[j][2] = (1.0f - wx) * wy * ix0 * iy1;
        wgt[j][3] = wx * wy * ix1 * iy1;
    }

    // ---- phase 2: issue all 16 gathers back-to-back ----
    float tv[4][4];
#pragma unroll
    for (int j = 0; j < 4; ++j)
#pragma unroll
        for (int t = 0; t < 4; ++t) tv[j][t] = g2[adr[j][t]];

    // ---- phase 3: independent loads land under the gather latency ----
    float4 c0 = *(const float4*)(i1 + p4);
    float4 c1 = *(const float4*)(i1 + HW + p4);
    float4 c2 = *(const float4*)(i1 + 2 * HW + p4);
    float4 vm4 = *(const float4*)(vm + p4);
    float4 ev4[CC];
#pragma unroll
    for (int c = 0; c < CC; ++c) ev4[c] = *(const float4*)(evb + c * HW + p4);

    float g1a[4] = {
        0.299f * c0.x + 0.587f * c1.x + 0.114f * c2.x,
        0.299f * c0.y + 0.587f * c1.y + 0.114f * c2.y,
        0.299f * c0.z + 0.587f * c1.z + 0.114f * c2.z,
        0.299f * c0.w + 0.587f * c1.w + 0.114f * c2.w };
    float vma[4] = { vm4.x, vm4.y, vm4.z, vm4.w };

    // acc[0]=l1, acc[1]=masksum, acc[2 + c*5 + k]
    float acc[27];
#pragma unroll
    for (int i = 0; i < 27; ++i) acc[i] = 0.0f;

#pragma unroll
    for (int j = 0; j < 4; ++j) {
        float warp = tv[j][0] * wgt[j][0] + tv[j][1] * wgt[j][1]
                   + tv[j][2] * wgt[j][2] + tv[j][3] * wgt[j][3];

        float nc  = fast_tanh5(warp - g1a[j]);
        float pos = fmaxf(nc, 0.0f);
        float neg = fmaxf(-nc, 0.0f);

        float pr[CC];
        pr[0] = pos;
        pr[1] = neg;
        pr[2] = 0.25f * pos + 0.75f * neg;
        pr[3] = 0.50f * pos + 0.50f * neg;
        pr[4] = 0.75f * pos + 0.25f * neg;

        const int li = LPAD(4 * tid + j);
#pragma unroll
        for (int c = 0; c < CC; ++c) s_pr[c][li] = pr[c];

        float fx = fxa[j], fy = fya[j];
        float m = ((fx * fx + fy * fy) > 0.01f) ? vma[j] : 0.0f;
        acc[1] += m;

        const float ga[CC] = { ev4[0][j], ev4[1][j], ev4[2][j], ev4[3][j], ev4[4][j] };
#pragma unroll
        for (int c = 0; c < CC; ++c) {
            float pm = pr[c] * m;
            float gm = ga[c] * m;
            acc[0] += fabsf(pm - gm);
            acc[2 + c * 5 + 0] += pm;
            acc[2 + c * 5 + 1] += gm;
            acc[2 + c * 5 + 2] += pm * gm;
            acc[2 + c * 5 + 3] += pm * pm;
            acc[2 + c * 5 + 4] += gm * gm;
        }
    }

    // ---- wave reduce on the VALU (DPP), result in lane 63 ----
    const int lane = tid & 63;
    const int wid  = tid >> 6;
#pragma unroll
    for (int i = 0; i < 27; ++i) acc[i] = wave_sum_dpp(acc[i]);
    if (lane == 63) {
#pragma unroll
        for (int i = 0; i < 27; ++i) sdata[wid][i] = acc[i];
    }

    __syncthreads();   // single barrier: covers s_pr and sdata

    // re-staggered pred stores: out index = 1 + ... + px, so px = 4k+3 is 16B-aligned
#pragma unroll
    for (int c = 0; c < CC; ++c) {
        const float* sp = s_pr[c];
        float* ob = po + c * HW + P;
        if (tid < 255) {
            int i0 = 3 + 4 * tid;
            float4 v;
            v.x = sp[LPAD(i0)];
            v.y = sp[LPAD(i0 + 1)];
            v.z = sp[LPAD(i0 + 2)];
            v.w = sp[LPAD(i0 + 3)];
            *(float4*)(ob + i0) = v;
        } else {
            ob[0] = sp[LPAD(0)];
            ob[1] = sp[LPAD(1)];
            ob[2] = sp[LPAD(2)];
            ob[1023] = sp[LPAD(1023)];
        }
    }

    // ---- per-block partials: plain coalesced stores, NO atomics ----
    if (tid < 27) {
        float s = sdata[0][tid] + sdata[1][tid] + sdata[2][tid] + sdata[3][tid];
        partial[(size_t)(b * NBLK + blockIdx.x) * 32 + tid] = s;
    }
}

__global__ void k_reduce(const float* __restrict__ partial, double* __restrict__ stats) {
    // one block per (b, stat-index): 8*27 = 216 blocks of 64 threads
    int bi = blockIdx.x;
    int b = bi / 27;
    int i = bi - b * 27;
    int t = threadIdx.x;
    double s = 0.0;
    for (int k = t; k < NBLK; k += 64)
        s += (double)partial[(size_t)(b * NBLK + k) * 32 + i];
    for (int off = 32; off > 0; off >>= 1) s += __shfl_down(s, off, 64);
    if (t == 0) {
        if (i == 0)      stats[210 + b] = s;          // per-b L1 sum
        else if (i == 1) stats[1 + b] = s;            // per-b mask sum
        else             stats[9 + b * 25 + (i - 2)] = s;
    }
}

__global__ void k_final(const double* __restrict__ stats, float* __restrict__ out) {
    int t = threadIdx.x;  // 64 threads
    double contrib = 0.0;
    if (t < BB * CC) {
        int b = t / CC;
        int c = t - b * CC;
        const double* s = stats + 9 + b * 25 + c * 5;
        double Sp = s[0], Sg = s[1], Spg = s[2], Spp = s[3], Sgg = s[4];
        const double N = (double)HW;
        double num  = Spg - Sp * Sg / N;
        double varp = Spp - Sp * Sp / N; if (varp < 0.0) varp = 0.0;
        double varg = Sgg - Sg * Sg / N; if (varg < 0.0) varg = 0.0;
        double den  = sqrt(varp) * sqrt(varg) + 1e-6;
        double corr = num / den;
        bool valid = stats[1 + b] > 0.0;
        contrib = valid ? (1.0 - corr) : 0.0;
    }
    for (int off = 32; off > 0; off >>= 1) contrib += __shfl_down(contrib, off, 64);
    if (t == 0) {
        double msum_total = 0.0, l1sum = 0.0;
        for (int b = 0; b < BB; ++b) { msum_total += stats[1 + b]; l1sum += stats[210 + b]; }
        double mask_sum = (double)CC * msum_total + 1e-6;
        double l1_loss = l1sum / mask_sum;
        double corr_loss = contrib / (double)(BB * CC);
        out[0] = (float)(l1_loss + 0.5 * corr_loss);
    }
}

extern "C" void kernel_launch(void* const* d_in, const int* in_sizes, int n_in,
                              void* d_out, int out_size, void* d_ws, size_t ws_size,
                              hipStream_t stream) {
    const float* img1  = (const float*)d_in[0];
    const float* img2  = (const float*)d_in[1];
    const float* flow  = (const float*)d_in[2];
    const float* ev    = (const float*)d_in[3];
    const float* vmask = (const float*)d_in[4];
    float* out = (float*)d_out;

    double* stats   = (double*)d_ws;
    float*  partial = (float*)((char*)d_ws + PARTIAL_OFFSET);
    float*  gray2   = (float*)((char*)d_ws + GRAY2_OFFSET);

    int ngroups = BB * HW / 4;                       // 614400
    k_gray2<<<(ngroups + 255) / 256, 256, 0, stream>>>(img2, gray2);

    dim3 grid(NBLK, BB);                             // (300, 8)
    k_main<<<grid, 256, 0, stream>>>(img1, flow, ev, vmask, gray2, out + 1, partial);

    k_reduce<<<BB * 27, 64, 0, stream>>>(partial, stats);

    k_final<<<1, 64, 0, stream>>>(stats, out);
}